// Round 10
// baseline (447.082 us; speedup 1.0000x reference)
//
#include <hip/hip_runtime.h>
#include <hip/hip_bf16.h>

// CPSFMemcellAutoencoder: B=8, 256x256 input, N=16, S=128, M=32, T=131072.
// Workspace layout (~260 MB):
//   [0, 134217728)            a_s   : NC8HW8 [8][16 cig][65536 hw][8 ci] bf16
//   [134217728, 167772160)    t_star: [T,128] bf16 token-major
//   [201326592, 234881024)    a_n   : [8,16,256,256] f32 (n-branch)
//     REUSED: wt2  at +201326592 (294912 B, conv2_s weights bf16)
//     REUSED: part at +201850880 (1024 x 5120 f32 partials)
//   [234881024, 243269632)    z     : [T,16] f32
//   [243269632, 260046848)    wmat  : [T,32] f32
//   [260046848, 260050944)    WtW   : [32,32] f32
//   [260050944, 260067328)    WtT   : [32,128] f32
//   [260067328, 260083712)    cvn   : [32,128] f32
//   d0m  reuses [0, 67108864)        : [8,128,128,128] f32
//   dec1 reuses [67108864, 73400320) : [8,3,256,256] f32

#define ALPHA_F 1e-6f

typedef __attribute__((ext_vector_type(8))) short bf16x8;
typedef __attribute__((ext_vector_type(4))) float f32x4;

__device__ __forceinline__ float silu_f(float x) {
    return x / (1.f + __expf(-x));
}

__device__ __forceinline__ short f2bf(float f) {
    __hip_bfloat16 h = __float2bfloat16(f);
    union { __hip_bfloat16 b; short s; } u; u.b = h; return u.s;
}

__device__ __forceinline__ float bf2f(unsigned short s) {
    union { unsigned u; float f; } c; c.u = (unsigned)s << 16; return c.f;
}

// ---------------- conv 3x3, Cin=3, stride 1, pad 1, + bias + silu (NCHW f32 out) ----------------
template<int CO>
__global__ __launch_bounds__(256) void conv1_silu(
    const float* __restrict__ x, const float* __restrict__ wgt,
    const float* __restrict__ bias, float* __restrict__ out)
{
    int idx = blockIdx.x * 256 + threadIdx.x;      // (b,h,w)
    int w = idx & 255, h = (idx >> 8) & 255, b = idx >> 16;
    const float* xb = x + (size_t)b * 3 * 65536;
    float in[27];
#pragma unroll
    for (int ci = 0; ci < 3; ci++)
#pragma unroll
        for (int ky = 0; ky < 3; ky++)
#pragma unroll
            for (int kx = 0; kx < 3; kx++) {
                int hh = h + ky - 1, ww = w + kx - 1;
                bool ok = ((unsigned)hh < 256u) && ((unsigned)ww < 256u);
                in[(ci * 3 + ky) * 3 + kx] = ok ? xb[(ci << 16) + (hh << 8) + ww] : 0.f;
            }
    float* ob = out + (size_t)b * CO * 65536 + (h << 8) + w;
#pragma unroll 4
    for (int co = 0; co < CO; co++) {
        float acc = bias[co];          // uniform index -> s_load
#pragma unroll
        for (int k = 0; k < 27; k++) acc += in[k] * wgt[co * 27 + k];
        ob[(size_t)co << 16] = silu_f(acc);
    }
}

// ---------------- s-branch conv1 as single-K-step MFMA GEMM ----------------
#define C1K 40   // padded k-stride (shorts)
__global__ __launch_bounds__(256) void conv1s_mfma(
    const float* __restrict__ x, const float* __restrict__ wgt,
    const float* __restrict__ bias, __hip_bfloat16* __restrict__ out)
{
    __shared__ __align__(16) short Ps[128 * C1K];  // [pixel][k]
    __shared__ __align__(16) short Ws[128 * C1K];  // [co][k]
    int tid = threadIdx.x;
    int g = blockIdx.x;                 // 4096: b*512 + rem
    int b = g >> 9, rem = g & 511;
    int h = rem >> 1, w0 = (rem & 1) * 128;

    union { short s[32]; float4 v4[4]; } row;
#pragma unroll
    for (int k = 0; k < 32; k++) row.s[k] = 0;
    if (tid < 128) {
        int wpix = w0 + tid;
        const float* xb = x + (size_t)b * 3 * 65536;
#pragma unroll
        for (int ci = 0; ci < 3; ci++)
#pragma unroll
            for (int ky = 0; ky < 3; ky++)
#pragma unroll
                for (int kx = 0; kx < 3; kx++) {
                    int hh = h + ky - 1, ww = wpix + kx - 1;
                    float v = 0.f;
                    if (((unsigned)hh < 256u) && ((unsigned)ww < 256u))
                        v = xb[(ci << 16) + (hh << 8) + ww];
                    row.s[ci * 9 + ky * 3 + kx] = f2bf(v);
                }
#pragma unroll
        for (int j = 0; j < 4; j++) *(float4*)&Ps[tid * C1K + j * 8] = row.v4[j];
    } else {
        int co = tid - 128;
#pragma unroll
        for (int k = 0; k < 27; k++) row.s[k] = f2bf(wgt[co * 27 + k]);
#pragma unroll
        for (int j = 0; j < 4; j++) *(float4*)&Ws[co * C1K + j * 8] = row.v4[j];
    }
    __syncthreads();

    int lane = tid & 63, wave = tid >> 6;
    int coH = (wave & 1) * 64, pxH = (wave >> 1) * 64;
    int r16 = lane & 15, koff = (lane >> 4) * 8;
    bf16x8 af[4], bfr[4];
#pragma unroll
    for (int mt = 0; mt < 4; mt++)
        af[mt] = *(bf16x8*)&Ws[(coH + mt * 16 + r16) * C1K + koff];
#pragma unroll
    for (int nt = 0; nt < 4; nt++)
        bfr[nt] = *(bf16x8*)&Ps[(pxH + nt * 16 + r16) * C1K + koff];
    f32x4 acc[4][4];
#pragma unroll
    for (int mt = 0; mt < 4; mt++)
#pragma unroll
        for (int nt = 0; nt < 4; nt++) {
#pragma unroll
            for (int r = 0; r < 4; r++) acc[mt][nt][r] = 0.f;
            acc[mt][nt] = __builtin_amdgcn_mfma_f32_16x16x32_bf16(
                af[mt], bfr[nt], acc[mt][nt], 0, 0, 0);
        }

    __hip_bfloat16* ob = out + (size_t)b * 16 * 65536 * 8;
#pragma unroll
    for (int mt = 0; mt < 4; mt++) {
        int cb = coH + mt * 16 + (lane >> 4) * 4;
        float4 bv = *(const float4*)&bias[cb];
        float bvals[4] = {bv.x, bv.y, bv.z, bv.w};
        int cig = cb >> 3, cof = cb & 7;
#pragma unroll
        for (int nt = 0; nt < 4; nt++) {
            int p = pxH + nt * 16 + r16;
            int hw = (h << 8) + w0 + p;
            union { short s[4]; float2 v; } u;
#pragma unroll
            for (int r = 0; r < 4; r++)
                u.s[r] = f2bf(silu_f(acc[mt][nt][r] + bvals[r]));
            *(float2*)&ob[((size_t)cig * 65536 + hw) * 8 + cof] = u.v;
        }
    }
}

// ---------------- weight prep: Wt[pos][co][ci] bf16 from W[co][ci][ky][kx] f32 ----------------
__global__ __launch_bounds__(256) void wprep_kern(
    const float* __restrict__ w, __hip_bfloat16* __restrict__ wt)
{
    int i = blockIdx.x * 256 + threadIdx.x;        // 147456
    int pos = i >> 14, rem = i & 16383;
    int co = rem >> 7, ci = rem & 127;
    wt[i] = __float2bfloat16(w[co * 1152 + ci * 9 + pos]);
}

// ------------- conv2_s implicit GEMM v10: LDS-free, barrier-free direct-fragment loads -------------
// R9 post-mortem: LDS pipe (~6.9k b128 wave-ops/CU x ~17 cyc = ~50us) + 36 barrier-pairs was
// the bottleneck (MfmaUtil 15%, all pipes <40%). Both MFMA operand layouts are 16B-contiguous
// in memory: A[m=lane&15][k=q*8..+7] = one NC8HW8 ci8-group; B[n=lane&15][k=q*8..+7] = 16B of
// wt[pos][co][ci]. So load fragments straight from global (L2-hot for B: 288KB total),
// zero LDS, zero __syncthreads, zero bank conflicts, no spill-forcing live ranges.
// Block = one (b,h2) row of 128 tokens; 4 waves in 2x2 grid; wave = 64tok x 64co.
__global__ __launch_bounds__(256) void conv2s_mfma(
    const __hip_bfloat16* __restrict__ a_s,   // NC8HW8 [8][16][65536][8]
    const __hip_bfloat16* __restrict__ wt,    // [9][128co][128ci]
    const float* __restrict__ bias, __hip_bfloat16* __restrict__ out)  // [T][128] bf16
{
    int tid = threadIdx.x;
    int g = blockIdx.x;                 // 1024: b*128 + h2
    int b = g >> 7, h2 = g & 127;
    int lane = tid & 63, wave = tid >> 6;
    int mh = wave & 1, nh = wave >> 1;
    int mrow = lane & 15, q = lane >> 4;

    f32x4 acc[4][4];   // [nt][mt]
#pragma unroll
    for (int i = 0; i < 4; i++)
#pragma unroll
        for (int j = 0; j < 4; j++)
#pragma unroll
            for (int r = 0; r < 4; r++) acc[i][j][r] = 0.f;

    bf16x8 zero8;
#pragma unroll
    for (int j = 0; j < 8; j++) zero8[j] = 0;

    const float4* ab8 = (const float4*)a_s + (size_t)b * 16 * 65536;
    const float4* wb8 = (const float4*)wt;
    // per-lane bases
    int xb[4];
#pragma unroll
    for (int mt = 0; mt < 4; mt++)
        xb[mt] = 2 * (mh * 64 + mt * 16 + mrow) - 1;   // + kx, always < 256
    int cb0 = (nh * 64 + mrow) * 16 + q;               // float4 idx of (co, ci=q*8)

#pragma unroll 1
    for (int pos = 0; pos < 9; pos++) {
        int ky = pos / 3, kx = pos - 3 * ky;     // uniform
        int y = 2 * h2 - 1 + ky;
        if ((unsigned)y >= 256u) continue;       // uniform skip, no barrier in loop
        const float4* arow = ab8 + ((size_t)y << 8);
        const float4* wrow = wb8 + pos * 2048;
#pragma unroll
        for (int cc = 0; cc < 4; cc++) {
            int cig = cc * 4 + q;
            bf16x8 afr[4], bfr[4];
#pragma unroll
            for (int mt = 0; mt < 4; mt++) {
                int x = xb[mt] + kx;
                bf16x8 v = zero8;
                if (x >= 0) v = *(const bf16x8*)&arow[((size_t)cig << 16) + x];
                afr[mt] = v;
            }
#pragma unroll
            for (int nt = 0; nt < 4; nt++)
                bfr[nt] = *(const bf16x8*)&wrow[cb0 + nt * 256 + cc * 4];
#pragma unroll
            for (int nt = 0; nt < 4; nt++)
#pragma unroll
                for (int mt = 0; mt < 4; mt++)
                    acc[nt][mt] = __builtin_amdgcn_mfma_f32_16x16x32_bf16(
                        afr[mt], bfr[nt], acc[nt][mt], 0, 0, 0);
        }
    }
    // epilogue: D[row=token=q*4+r (+16mt+64mh)][col=co=mrow (+16nt+64nh)]
    size_t tokbase = (size_t)g * 128 + mh * 64;
#pragma unroll
    for (int nt = 0; nt < 4; nt++) {
        int co = nh * 64 + nt * 16 + mrow;
        float bvs = bias[co];
#pragma unroll
        for (int mt = 0; mt < 4; mt++) {
            int m0 = mt * 16 + q * 4;
#pragma unroll
            for (int r = 0; r < 4; r++)
                out[(tokbase + m0 + r) * 128 + co] =
                    __float2bfloat16(silu_f(acc[nt][mt][r] + bvs));
        }
    }
}

// ------------- conv 3x3, stride 2, pad 1, + bias + silu, token-major out (n-branch) -------------
template<int CI, int CO>
__global__ __launch_bounds__(256) void conv2s2_silu(
    const float* __restrict__ in, const float* __restrict__ wgt,
    const float* __restrict__ bias, float* __restrict__ out)
{
    int idx = blockIdx.x * 256 + threadIdx.x;      // token (b,h2,w2)
    int w2 = idx & 127, h2 = (idx >> 7) & 127, b = idx >> 14;
    const float* ib = in + (size_t)b * CI * 65536;
    float acc[CO];
#pragma unroll
    for (int co = 0; co < CO; co++) acc[co] = bias[co];
    int h0 = 2 * h2 - 1, w0 = 2 * w2 - 1;
    for (int ci = 0; ci < CI; ci++) {
        float t[9];
#pragma unroll
        for (int ky = 0; ky < 3; ky++)
#pragma unroll
            for (int kx = 0; kx < 3; kx++) {
                int hh = h0 + ky, ww = w0 + kx;
                bool ok = ((unsigned)hh < 256u) && ((unsigned)ww < 256u);
                t[ky * 3 + kx] = ok ? ib[((size_t)ci << 16) + (hh << 8) + ww] : 0.f;
            }
#pragma unroll
        for (int co = 0; co < CO; co++)
#pragma unroll
            for (int k = 0; k < 9; k++)
                acc[co] += t[k] * wgt[(co * CI + ci) * 9 + k];
    }
    float* ob = out + (size_t)idx * CO;
#pragma unroll
    for (int co = 0; co < CO; co++) ob[co] = silu_f(acc[co]);
}

// ---------------- softmax(z @ cell_k^T / 4) -> w [T,32] ----------------
__global__ __launch_bounds__(256) void memcell_w_kern(
    const float* __restrict__ z, const float* __restrict__ ck, float* __restrict__ wout)
{
    int t = blockIdx.x * 256 + threadIdx.x;
    float zv[16];
    const float4* zp = (const float4*)(z + (size_t)t * 16);
#pragma unroll
    for (int i = 0; i < 4; i++) {
        float4 v = zp[i];
        zv[4 * i] = v.x; zv[4 * i + 1] = v.y; zv[4 * i + 2] = v.z; zv[4 * i + 3] = v.w;
    }
    float lg[32]; float mx = -1e30f;
#pragma unroll
    for (int m = 0; m < 32; m++) {
        float a = 0.f;
#pragma unroll
        for (int n = 0; n < 16; n++) a += zv[n] * ck[m * 16 + n];
        a *= 0.25f;
        lg[m] = a; mx = fmaxf(mx, a);
    }
    float s = 0.f;
#pragma unroll
    for (int m = 0; m < 32; m++) { lg[m] = __expf(lg[m] - mx); s += lg[m]; }
    float inv = 1.f / s;
    float4* wp = (float4*)(wout + (size_t)t * 32);
#pragma unroll
    for (int m = 0; m < 8; m++)
        wp[m] = make_float4(lg[4 * m] * inv, lg[4 * m + 1] * inv,
                            lg[4 * m + 2] * inv, lg[4 * m + 3] * inv);
}

// ---------------- WtW/WtT partials: 1024 blocks x 128 tokens, no atomics ----------------
__global__ __launch_bounds__(256) void memcell_acc_kern(
    const float* __restrict__ wmat, const __hip_bfloat16* __restrict__ tstar,
    float* __restrict__ part)
{
    __shared__ float ws[64][32];     // 8 KB
    __shared__ float ts[64 * 128];   // 32 KB
    int tid = threadIdx.x;
    int sg = tid & 31, mg = tid >> 5;
    int mW = tid & 31, m2 = (tid >> 5) * 4;
    float accT[16], accW[4];
#pragma unroll
    for (int i = 0; i < 16; i++) accT[i] = 0.f;
#pragma unroll
    for (int i = 0; i < 4; i++) accW[i] = 0.f;

#pragma unroll 1
    for (int cc = 0; cc < 2; cc++) {
        int c = blockIdx.x * 2 + cc;
        size_t base = (size_t)c * 64;
        __syncthreads();
        {
            const float4* src = (const float4*)(wmat + base * 32);
            float4* dst = (float4*)&ws[0][0];
#pragma unroll
            for (int i = 0; i < 2; i++) dst[tid + 256 * i] = src[tid + 256 * i];
            const float4* src2 = (const float4*)(tstar + base * 128);
#pragma unroll
            for (int i = 0; i < 4; i++) {
                union { float4 v; unsigned short us[8]; } u;
                u.v = src2[tid + 256 * i];
                float* d = &ts[(tid + 256 * i) * 8];
                float4 lo = make_float4(bf2f(u.us[0]), bf2f(u.us[1]), bf2f(u.us[2]), bf2f(u.us[3]));
                float4 hi = make_float4(bf2f(u.us[4]), bf2f(u.us[5]), bf2f(u.us[6]), bf2f(u.us[7]));
                *(float4*)d = lo; *(float4*)(d + 4) = hi;
            }
        }
        __syncthreads();
        for (int t = 0; t < 64; t++) {
            float4 wv = *(const float4*)&ws[t][mg * 4];
            float4 sv = *(const float4*)&ts[t * 128 + sg * 4];
            accT[0]  += wv.x * sv.x; accT[1]  += wv.x * sv.y; accT[2]  += wv.x * sv.z; accT[3]  += wv.x * sv.w;
            accT[4]  += wv.y * sv.x; accT[5]  += wv.y * sv.y; accT[6]  += wv.y * sv.z; accT[7]  += wv.y * sv.w;
            accT[8]  += wv.z * sv.x; accT[9]  += wv.z * sv.y; accT[10] += wv.z * sv.z; accT[11] += wv.z * sv.w;
            accT[12] += wv.w * sv.x; accT[13] += wv.w * sv.y; accT[14] += wv.w * sv.z; accT[15] += wv.w * sv.w;
            float wa = ws[t][mW];
            float4 wb = *(const float4*)&ws[t][m2];
            accW[0] += wa * wb.x; accW[1] += wa * wb.y;
            accW[2] += wa * wb.z; accW[3] += wa * wb.w;
        }
    }
    float* pb = part + (size_t)blockIdx.x * 5120;
#pragma unroll
    for (int i = 0; i < 16; i++) pb[i * 256 + tid] = accT[i];
#pragma unroll
    for (int i = 0; i < 4; i++) pb[4096 + i * 256 + tid] = accW[i];
}

// ---------------- reduce 1024 partials -> WtT [32,128], WtW [32,32] ----------------
__global__ __launch_bounds__(256) void memcell_reduce_kern(
    const float* __restrict__ part, float* __restrict__ WtT, float* __restrict__ WtW)
{
    int gid = blockIdx.x * 256 + threadIdx.x;   // 81920
    int j = gid % 5120, seg = gid / 5120;
    const float* p = part + (size_t)seg * 64 * 5120 + j;
    float s = 0.f;
#pragma unroll 8
    for (int k = 0; k < 64; k++) s += p[(size_t)k * 5120];
    int i = j >> 8, t = j & 255;
    if (j < 4096) {
        int sg = t & 31, mg = t >> 5;
        atomicAdd(&WtT[(mg * 4 + (i >> 2)) * 128 + sg * 4 + (i & 3)], s);
    } else {
        int i2 = i - 16;
        int mW = t & 31, m2 = (t >> 5) * 4;
        atomicAdd(&WtW[mW * 32 + m2 + i2], s);
    }
}

// ------- cell_v_new = cell_v + ALPHA*(WtT - WtW @ cell_v)  [32,128] -------
__global__ __launch_bounds__(256) void cvnew_kern(
    const float* __restrict__ cv, const float* __restrict__ WtW,
    const float* __restrict__ WtT, float* __restrict__ cvn)
{
    int idx = blockIdx.x * 256 + threadIdx.x;   // 4096
    int s = idx & 127, m = idx >> 7;
    float g = WtT[idx];
#pragma unroll
    for (int j = 0; j < 32; j++) g -= WtW[m * 32 + j] * cv[j * 128 + s];
    cvn[idx] = cv[idx] + ALPHA_F * g;
}

// ------- t_read = w @ cell_v_new, scattered to NCHW d0m [8,128,128,128] -------
__global__ __launch_bounds__(256) void memcell_read_kern(
    const float* __restrict__ wmat, const float* __restrict__ cvn, float* __restrict__ d0m)
{
    int t = blockIdx.x * 256 + threadIdx.x;
    int w2 = t & 127, h2 = (t >> 7) & 127, b = t >> 14;
    float wv[32];
    const float4* wp = (const float4*)(wmat + (size_t)t * 32);
#pragma unroll
    for (int i = 0; i < 8; i++) {
        float4 v = wp[i];
        wv[4 * i] = v.x; wv[4 * i + 1] = v.y; wv[4 * i + 2] = v.z; wv[4 * i + 3] = v.w;
    }
    float* ob = d0m + (size_t)b * 128 * 16384 + (h2 << 7) + w2;
    for (int s = 0; s < 128; s++) {
        float a = 0.f;
#pragma unroll
        for (int m = 0; m < 32; m++) a += wv[m] * cvn[m * 128 + s];
        ob[(size_t)s * 16384] = a;
    }
}

// ------- ConvTranspose2d(128->3, k4, s2, p1) + bias + silu, all 4 parities/thread -------
__global__ __launch_bounds__(256) void deconv_silu_kern(
    const float* __restrict__ in, const float* __restrict__ dw,
    const float* __restrict__ db, float* __restrict__ out)
{
    int g = blockIdx.x;                   // 512: b*64 + hb*8 + wb
    int wb = g & 7, hb = (g >> 3) & 7, b = g >> 6;
    int tx = threadIdx.x & 15, ty = threadIdx.x >> 4;
    int h2 = hb * 16 + ty, w2 = wb * 16 + tx;

    float mh[3], mw[3];
    int ihc[3], iwc[3];
#pragma unroll
    for (int a = 0; a < 3; a++) {
        int v = h2 - 1 + a;
        mh[a] = ((unsigned)v < 128u) ? 1.f : 0.f;
        ihc[a] = v < 0 ? 0 : (v > 127 ? 127 : v);
        v = w2 - 1 + a;
        mw[a] = ((unsigned)v < 128u) ? 1.f : 0.f;
        iwc[a] = v < 0 ? 0 : (v > 127 ? 127 : v);
    }
    const float* base = in + (size_t)b * 128 * 16384;
    const float* p[3][3];
    float msk[3][3];
#pragma unroll
    for (int a = 0; a < 3; a++)
#pragma unroll
        for (int c = 0; c < 3; c++) {
            p[a][c] = base + (ihc[a] << 7) + iwc[c];
            msk[a][c] = mh[a] * mw[c];
        }

    float acc[2][2][3];
#pragma unroll
    for (int ph = 0; ph < 2; ph++)
#pragma unroll
        for (int pw = 0; pw < 2; pw++)
#pragma unroll
            for (int co = 0; co < 3; co++) acc[ph][pw][co] = db[co];

    const int RA[4] = {0, 1, 1, 2}, RP[4] = {0, 0, 1, 1}, RK[4] = {3, 1, 2, 0};

    for (int ci = 0; ci < 128; ci++) {
        float t[3][3];
#pragma unroll
        for (int a = 0; a < 3; a++)
#pragma unroll
            for (int c = 0; c < 3; c++)
                t[a][c] = msk[a][c] * p[a][c][(size_t)ci << 14];
        const float* wc = dw + ci * 48;
#pragma unroll
        for (int ri = 0; ri < 4; ri++)
#pragma unroll
            for (int cj = 0; cj < 4; cj++) {
                float tv = t[RA[ri]][RA[cj]];
                int ph = RP[ri], pw = RP[cj];
                int widx = RK[ri] * 4 + RK[cj];
#pragma unroll
                for (int co = 0; co < 3; co++)
                    acc[ph][pw][co] += tv * wc[co * 16 + widx];
            }
    }
    int h = 2 * h2, w = 2 * w2;
#pragma unroll
    for (int ph = 0; ph < 2; ph++)
#pragma unroll
        for (int co = 0; co < 3; co++) {
            float2 v = make_float2(silu_f(acc[ph][0][co]), silu_f(acc[ph][1][co]));
            *(float2*)&out[(size_t)b * 3 * 65536 + (size_t)co * 65536 + ((size_t)(h + ph) << 8) + w] = v;
        }
}

extern "C" void kernel_launch(void* const* d_in, const int* in_sizes, int n_in,
                              void* d_out, int out_size, void* d_ws, size_t ws_size,
                              hipStream_t stream)
{
    const float* x      = (const float*)d_in[0];
    const float* e0n_w1 = (const float*)d_in[1];
    const float* e0n_b1 = (const float*)d_in[2];
    const float* e0n_w2 = (const float*)d_in[3];
    const float* e0n_b2 = (const float*)d_in[4];
    const float* e0s_w1 = (const float*)d_in[5];
    const float* e0s_b1 = (const float*)d_in[6];
    const float* e0s_w2 = (const float*)d_in[7];
    const float* e0s_b2 = (const float*)d_in[8];
    const float* d0_dw  = (const float*)d_in[9];
    const float* d0_db  = (const float*)d_in[10];
    const float* d0_cw  = (const float*)d_in[11];
    const float* d0_cb  = (const float*)d_in[12];
    const float* cell_k = (const float*)d_in[13];
    const float* cell_v = (const float*)d_in[14];
    float* outp = (float*)d_out;

    char* ws = (char*)d_ws;
    __hip_bfloat16* a_s    = (__hip_bfloat16*)(ws);
    __hip_bfloat16* t_star = (__hip_bfloat16*)(ws + 134217728);
    float* a_n    = (float*)(ws + 201326592);
    __hip_bfloat16* wt2 = (__hip_bfloat16*)(ws + 201326592);  // reuses a_n after conv2_n
    float* part   = (float*)(ws + 201850880);                 // 21 MB partials (a_n dead)
    float* z      = (float*)(ws + 234881024);
    float* wmat   = (float*)(ws + 243269632);
    float* WtW    = (float*)(ws + 260046848);
    float* WtT    = (float*)(ws + 260050944);
    float* cvn    = (float*)(ws + 260067328);
    float* d0m    = (float*)(ws);               // reuse a_s region
    float* dec1   = (float*)(ws + 67108864);    // reuse a_s region (tail)

    // n-branch encoder (a_n dead after conv2s2_silu)
    conv1_silu<16><<<2048, 256, 0, stream>>>(x, e0n_w1, e0n_b1, a_n);
    conv2s2_silu<16, 16><<<512, 256, 0, stream>>>(a_n, e0n_w2, e0n_b2, z);
    // s-branch encoder: NC8HW8 MFMA conv1 -> LDS-free MFMA implicit-GEMM conv2 (bf16 t_star out)
    wprep_kern<<<576, 256, 0, stream>>>(e0s_w2, wt2);
    conv1s_mfma<<<4096, 256, 0, stream>>>(x, e0s_w1, e0s_b1, a_s);
    conv2s_mfma<<<1024, 256, 0, stream>>>(a_s, wt2, e0s_b2, t_star);
    // memcell
    memcell_w_kern<<<512, 256, 0, stream>>>(z, cell_k, wmat);
    hipMemsetAsync(WtW, 0, (1024 + 4096) * sizeof(float), stream);
    memcell_acc_kern<<<1024, 256, 0, stream>>>(wmat, t_star, part);
    memcell_reduce_kern<<<320, 256, 0, stream>>>(part, WtT, WtW);
    cvnew_kern<<<16, 256, 0, stream>>>(cell_v, WtW, WtT, cvn);
    memcell_read_kern<<<512, 256, 0, stream>>>(wmat, cvn, d0m);
    // decoder
    deconv_silu_kern<<<512, 256, 0, stream>>>(d0m, d0_dw, d0_db, dec1);
    conv1_silu<3><<<2048, 256, 0, stream>>>(dec1, d0_cw, d0_cb, outp);
}

// Round 11
// 403.736 us; speedup vs baseline: 1.1074x; 1.1074x over previous
//
#include <hip/hip_runtime.h>
#include <hip/hip_bf16.h>

// CPSFMemcellAutoencoder: B=8, 256x256 input, N=16, S=128, M=32, T=131072.
// Workspace layout (~260 MB):
//   [0, 134217728)            a_s   : NC8HW8 [8][16 cig][65536 hw][8 ci] bf16
//   [134217728, 167772160)    t_star: [T,128] bf16 token-major
//   [201326592, 234881024)    a_n   : [8,16,256,256] f32 (n-branch)
//     REUSED: wt2  at +201326592 (294912 B, conv2_s weights bf16)
//     REUSED: part at +201850880 (1024 x 5120 f32 partials)
//   [234881024, 243269632)    z     : [T,16] f32
//   [243269632, 260046848)    wmat  : [T,32] f32
//   [260046848, 260050944)    WtW   : [32,32] f32
//   [260050944, 260067328)    WtT   : [32,128] f32
//   [260067328, 260083712)    cvn   : [32,128] f32
//   d0m  reuses [0, 67108864)        : [8,128,128,128] f32
//   dec1 reuses [67108864, 73400320) : [8,3,256,256] f32

#define ALPHA_F 1e-6f

typedef __attribute__((ext_vector_type(8))) short bf16x8;
typedef __attribute__((ext_vector_type(4))) float f32x4;

__device__ __forceinline__ float silu_f(float x) {
    return x / (1.f + __expf(-x));
}

__device__ __forceinline__ short f2bf(float f) {
    __hip_bfloat16 h = __float2bfloat16(f);
    union { __hip_bfloat16 b; short s; } u; u.b = h; return u.s;
}

__device__ __forceinline__ float bf2f(unsigned short s) {
    union { unsigned u; float f; } c; c.u = (unsigned)s << 16; return c.f;
}

// ---------------- conv 3x3, Cin=3, stride 1, pad 1, + bias + silu (NCHW f32 out) ----------------
template<int CO>
__global__ __launch_bounds__(256) void conv1_silu(
    const float* __restrict__ x, const float* __restrict__ wgt,
    const float* __restrict__ bias, float* __restrict__ out)
{
    int idx = blockIdx.x * 256 + threadIdx.x;      // (b,h,w)
    int w = idx & 255, h = (idx >> 8) & 255, b = idx >> 16;
    const float* xb = x + (size_t)b * 3 * 65536;
    float in[27];
#pragma unroll
    for (int ci = 0; ci < 3; ci++)
#pragma unroll
        for (int ky = 0; ky < 3; ky++)
#pragma unroll
            for (int kx = 0; kx < 3; kx++) {
                int hh = h + ky - 1, ww = w + kx - 1;
                bool ok = ((unsigned)hh < 256u) && ((unsigned)ww < 256u);
                in[(ci * 3 + ky) * 3 + kx] = ok ? xb[(ci << 16) + (hh << 8) + ww] : 0.f;
            }
    float* ob = out + (size_t)b * CO * 65536 + (h << 8) + w;
#pragma unroll 4
    for (int co = 0; co < CO; co++) {
        float acc = bias[co];          // uniform index -> s_load
#pragma unroll
        for (int k = 0; k < 27; k++) acc += in[k] * wgt[co * 27 + k];
        ob[(size_t)co << 16] = silu_f(acc);
    }
}

// ---------------- s-branch conv1 as single-K-step MFMA GEMM ----------------
#define C1K 40   // padded k-stride (shorts)
__global__ __launch_bounds__(256) void conv1s_mfma(
    const float* __restrict__ x, const float* __restrict__ wgt,
    const float* __restrict__ bias, __hip_bfloat16* __restrict__ out)
{
    __shared__ __align__(16) short Ps[128 * C1K];  // [pixel][k]
    __shared__ __align__(16) short Ws[128 * C1K];  // [co][k]
    int tid = threadIdx.x;
    int g = blockIdx.x;                 // 4096: b*512 + rem
    int b = g >> 9, rem = g & 511;
    int h = rem >> 1, w0 = (rem & 1) * 128;

    union { short s[32]; float4 v4[4]; } row;
#pragma unroll
    for (int k = 0; k < 32; k++) row.s[k] = 0;
    if (tid < 128) {
        int wpix = w0 + tid;
        const float* xb = x + (size_t)b * 3 * 65536;
#pragma unroll
        for (int ci = 0; ci < 3; ci++)
#pragma unroll
            for (int ky = 0; ky < 3; ky++)
#pragma unroll
                for (int kx = 0; kx < 3; kx++) {
                    int hh = h + ky - 1, ww = wpix + kx - 1;
                    float v = 0.f;
                    if (((unsigned)hh < 256u) && ((unsigned)ww < 256u))
                        v = xb[(ci << 16) + (hh << 8) + ww];
                    row.s[ci * 9 + ky * 3 + kx] = f2bf(v);
                }
#pragma unroll
        for (int j = 0; j < 4; j++) *(float4*)&Ps[tid * C1K + j * 8] = row.v4[j];
    } else {
        int co = tid - 128;
#pragma unroll
        for (int k = 0; k < 27; k++) row.s[k] = f2bf(wgt[co * 27 + k]);
#pragma unroll
        for (int j = 0; j < 4; j++) *(float4*)&Ws[co * C1K + j * 8] = row.v4[j];
    }
    __syncthreads();

    int lane = tid & 63, wave = tid >> 6;
    int coH = (wave & 1) * 64, pxH = (wave >> 1) * 64;
    int r16 = lane & 15, koff = (lane >> 4) * 8;
    bf16x8 af[4], bfr[4];
#pragma unroll
    for (int mt = 0; mt < 4; mt++)
        af[mt] = *(bf16x8*)&Ws[(coH + mt * 16 + r16) * C1K + koff];
#pragma unroll
    for (int nt = 0; nt < 4; nt++)
        bfr[nt] = *(bf16x8*)&Ps[(pxH + nt * 16 + r16) * C1K + koff];
    f32x4 acc[4][4];
#pragma unroll
    for (int mt = 0; mt < 4; mt++)
#pragma unroll
        for (int nt = 0; nt < 4; nt++) {
#pragma unroll
            for (int r = 0; r < 4; r++) acc[mt][nt][r] = 0.f;
            acc[mt][nt] = __builtin_amdgcn_mfma_f32_16x16x32_bf16(
                af[mt], bfr[nt], acc[mt][nt], 0, 0, 0);
        }

    __hip_bfloat16* ob = out + (size_t)b * 16 * 65536 * 8;
#pragma unroll
    for (int mt = 0; mt < 4; mt++) {
        int cb = coH + mt * 16 + (lane >> 4) * 4;
        float4 bv = *(const float4*)&bias[cb];
        float bvals[4] = {bv.x, bv.y, bv.z, bv.w};
        int cig = cb >> 3, cof = cb & 7;
#pragma unroll
        for (int nt = 0; nt < 4; nt++) {
            int p = pxH + nt * 16 + r16;
            int hw = (h << 8) + w0 + p;
            union { short s[4]; float2 v; } u;
#pragma unroll
            for (int r = 0; r < 4; r++)
                u.s[r] = f2bf(silu_f(acc[mt][nt][r] + bvals[r]));
            *(float2*)&ob[((size_t)cig * 65536 + hw) * 8 + cof] = u.v;
        }
    }
}

// ---------------- weight prep: Wt[pos][co][ci] bf16 from W[co][ci][ky][kx] f32 ----------------
__global__ __launch_bounds__(256) void wprep_kern(
    const float* __restrict__ w, __hip_bfloat16* __restrict__ wt)
{
    int i = blockIdx.x * 256 + threadIdx.x;        // 147456
    int pos = i >> 14, rem = i & 16383;
    int co = rem >> 7, ci = rem & 127;
    wt[i] = __float2bfloat16(w[co * 1152 + ci * 9 + pos]);
}

// ------------- conv2_s implicit GEMM v11: R6 structure, K=64 per barrier-pair -------------
// R10 post-mortem: LDS-free direct loads are wave-uncoalesced (B lanes 256B apart -> ~64
// L1 transactions/load) -> 155us. Staging through LDS is required for coalescing.
// This is R6's proven 64tok x 128co / 2048-block kernel with K=64 stages (18 barrier-pairs
// vs 72; 16 MFMAs/wave per pair vs 8). Spill rule (R7/R8/R9 evidence): hold exactly
// 2A+2B float4 across the barrier; remaining 2B loaded after sync with short live range.
// Row stride 72 shorts = 144B == 16 mod 128 -> 2-way max bank aliasing (free, m136).
#define TK64 72
__global__ __launch_bounds__(256) void conv2s_mfma(
    const __hip_bfloat16* __restrict__ a_s,   // NC8HW8 [8][16][65536][8]
    const __hip_bfloat16* __restrict__ wt,    // [9][128co][128ci]
    const float* __restrict__ bias, __hip_bfloat16* __restrict__ out)  // [T][128] bf16
{
    __shared__ __align__(16) short As[64 * TK64];    //  9216 B
    __shared__ __align__(16) short Bs[128 * TK64];   // 18432 B
    int tid = threadIdx.x;
    int g = blockIdx.x;                 // 2048: b*256 + h2*2 + half
    int b = g >> 8, h2 = (g >> 1) & 127, w2base = (g & 1) * 64;
    int lane = tid & 63, wave = tid >> 6;
    int mrow = lane & 15, q = lane >> 4;

    f32x4 acc[2][4];   // [nt][mt]
#pragma unroll
    for (int i = 0; i < 2; i++)
#pragma unroll
        for (int j = 0; j < 4; j++)
#pragma unroll
            for (int r = 0; r < 4; r++) acc[i][j][r] = 0.f;

    const float4* ab8 = (const float4*)a_s + (size_t)b * 16 * 65536;
    int tokA = tid >> 2, cqA = tid & 3;         // A staging: token, ci8-group
    int w2A = w2base + tokA;

#pragma unroll 1
    for (int pos = 0; pos < 9; pos++) {
        int ky = pos / 3, kx = pos - 3 * ky;    // uniform
        int y = 2 * h2 - 1 + ky;
        int x = 2 * w2A - 1 + kx;
        bool okA = ((unsigned)y < 256u) && ((unsigned)x < 256u);
        int pix = ((y & 255) << 8) + (x & 255);
        const float4* wp4 = (const float4*)(wt + (size_t)pos * 16384);
#pragma unroll 1
        for (int cc = 0; cc < 2; cc++) {        // ci chunks of 64
            // hold exactly 4 float4 across the barrier (spill rule)
            float4 a0 = make_float4(0.f, 0.f, 0.f, 0.f), a1 = a0;
            if (okA) {
                a0 = ab8[(size_t)(cc * 8 + cqA) << 16 | (unsigned)pix];
                a1 = ab8[(size_t)(cc * 8 + cqA + 4) << 16 | (unsigned)pix];
            }
            int s0 = tid, s1 = tid + 256;
            float4 b0 = wp4[(s0 >> 3) * 16 + cc * 8 + (s0 & 7)];
            float4 b1 = wp4[(s1 >> 3) * 16 + cc * 8 + (s1 & 7)];
            __syncthreads();                    // previous stage's LDS reads done
            *(float4*)&As[tokA * TK64 + cqA * 8]       = a0;
            *(float4*)&As[tokA * TK64 + (cqA + 4) * 8] = a1;
            *(float4*)&Bs[(s0 >> 3) * TK64 + (s0 & 7) * 8] = b0;
            *(float4*)&Bs[(s1 >> 3) * TK64 + (s1 & 7) * 8] = b1;
            // remaining B half: loaded after sync, short live range (no spill pressure)
            int s2 = tid + 512, s3 = tid + 768;
            float4 b2 = wp4[(s2 >> 3) * 16 + cc * 8 + (s2 & 7)];
            float4 b3 = wp4[(s3 >> 3) * 16 + cc * 8 + (s3 & 7)];
            *(float4*)&Bs[(s2 >> 3) * TK64 + (s2 & 7) * 8] = b2;
            *(float4*)&Bs[(s3 >> 3) * TK64 + (s3 & 7) * 8] = b3;
            __syncthreads();
#pragma unroll
            for (int c2 = 0; c2 < 2; c2++) {    // two K=32 halves of the staged 64
                int ko = c2 * 32 + q * 8;
                bf16x8 afr[4], bfr[2];
#pragma unroll
                for (int mt = 0; mt < 4; mt++)
                    afr[mt] = *(bf16x8*)&As[(mt * 16 + mrow) * TK64 + ko];
#pragma unroll
                for (int nt = 0; nt < 2; nt++)
                    bfr[nt] = *(bf16x8*)&Bs[(wave * 32 + nt * 16 + mrow) * TK64 + ko];
#pragma unroll
                for (int nt = 0; nt < 2; nt++)
#pragma unroll
                    for (int mt = 0; mt < 4; mt++)
                        acc[nt][mt] = __builtin_amdgcn_mfma_f32_16x16x32_bf16(
                            afr[mt], bfr[nt], acc[nt][mt], 0, 0, 0);
            }
        }
    }
    // epilogue: D[row=token=q*4+r (+16mt)][col=co=mrow (+16nt+32wave)]
    int rowg = q * 4;
    size_t tbase = (size_t)g * 64;
#pragma unroll
    for (int nt = 0; nt < 2; nt++) {
        int co = wave * 32 + nt * 16 + mrow;
        float bvs = bias[co];
#pragma unroll
        for (int mt = 0; mt < 4; mt++)
#pragma unroll
            for (int r = 0; r < 4; r++) {
                int m = mt * 16 + rowg + r;
                out[(tbase + m) * 128 + co] =
                    __float2bfloat16(silu_f(acc[nt][mt][r] + bvs));
            }
    }
}

// ------------- conv 3x3, stride 2, pad 1, + bias + silu, token-major out (n-branch) -------------
template<int CI, int CO>
__global__ __launch_bounds__(256) void conv2s2_silu(
    const float* __restrict__ in, const float* __restrict__ wgt,
    const float* __restrict__ bias, float* __restrict__ out)
{
    int idx = blockIdx.x * 256 + threadIdx.x;      // token (b,h2,w2)
    int w2 = idx & 127, h2 = (idx >> 7) & 127, b = idx >> 14;
    const float* ib = in + (size_t)b * CI * 65536;
    float acc[CO];
#pragma unroll
    for (int co = 0; co < CO; co++) acc[co] = bias[co];
    int h0 = 2 * h2 - 1, w0 = 2 * w2 - 1;
    for (int ci = 0; ci < CI; ci++) {
        float t[9];
#pragma unroll
        for (int ky = 0; ky < 3; ky++)
#pragma unroll
            for (int kx = 0; kx < 3; kx++) {
                int hh = h0 + ky, ww = w0 + kx;
                bool ok = ((unsigned)hh < 256u) && ((unsigned)ww < 256u);
                t[ky * 3 + kx] = ok ? ib[((size_t)ci << 16) + (hh << 8) + ww] : 0.f;
            }
#pragma unroll
        for (int co = 0; co < CO; co++)
#pragma unroll
            for (int k = 0; k < 9; k++)
                acc[co] += t[k] * wgt[(co * CI + ci) * 9 + k];
    }
    float* ob = out + (size_t)idx * CO;
#pragma unroll
    for (int co = 0; co < CO; co++) ob[co] = silu_f(acc[co]);
}

// ---------------- softmax(z @ cell_k^T / 4) -> w [T,32] ----------------
__global__ __launch_bounds__(256) void memcell_w_kern(
    const float* __restrict__ z, const float* __restrict__ ck, float* __restrict__ wout)
{
    int t = blockIdx.x * 256 + threadIdx.x;
    float zv[16];
    const float4* zp = (const float4*)(z + (size_t)t * 16);
#pragma unroll
    for (int i = 0; i < 4; i++) {
        float4 v = zp[i];
        zv[4 * i] = v.x; zv[4 * i + 1] = v.y; zv[4 * i + 2] = v.z; zv[4 * i + 3] = v.w;
    }
    float lg[32]; float mx = -1e30f;
#pragma unroll
    for (int m = 0; m < 32; m++) {
        float a = 0.f;
#pragma unroll
        for (int n = 0; n < 16; n++) a += zv[n] * ck[m * 16 + n];
        a *= 0.25f;
        lg[m] = a; mx = fmaxf(mx, a);
    }
    float s = 0.f;
#pragma unroll
    for (int m = 0; m < 32; m++) { lg[m] = __expf(lg[m] - mx); s += lg[m]; }
    float inv = 1.f / s;
    float4* wp = (float4*)(wout + (size_t)t * 32);
#pragma unroll
    for (int m = 0; m < 8; m++)
        wp[m] = make_float4(lg[4 * m] * inv, lg[4 * m + 1] * inv,
                            lg[4 * m + 2] * inv, lg[4 * m + 3] * inv);
}

// ---------------- WtW/WtT partials: 1024 blocks x 128 tokens, no atomics ----------------
__global__ __launch_bounds__(256) void memcell_acc_kern(
    const float* __restrict__ wmat, const __hip_bfloat16* __restrict__ tstar,
    float* __restrict__ part)
{
    __shared__ float ws[64][32];     // 8 KB
    __shared__ float ts[64 * 128];   // 32 KB
    int tid = threadIdx.x;
    int sg = tid & 31, mg = tid >> 5;
    int mW = tid & 31, m2 = (tid >> 5) * 4;
    float accT[16], accW[4];
#pragma unroll
    for (int i = 0; i < 16; i++) accT[i] = 0.f;
#pragma unroll
    for (int i = 0; i < 4; i++) accW[i] = 0.f;

#pragma unroll 1
    for (int cc = 0; cc < 2; cc++) {
        int c = blockIdx.x * 2 + cc;
        size_t base = (size_t)c * 64;
        __syncthreads();
        {
            const float4* src = (const float4*)(wmat + base * 32);
            float4* dst = (float4*)&ws[0][0];
#pragma unroll
            for (int i = 0; i < 2; i++) dst[tid + 256 * i] = src[tid + 256 * i];
            const float4* src2 = (const float4*)(tstar + base * 128);
#pragma unroll
            for (int i = 0; i < 4; i++) {
                union { float4 v; unsigned short us[8]; } u;
                u.v = src2[tid + 256 * i];
                float* d = &ts[(tid + 256 * i) * 8];
                float4 lo = make_float4(bf2f(u.us[0]), bf2f(u.us[1]), bf2f(u.us[2]), bf2f(u.us[3]));
                float4 hi = make_float4(bf2f(u.us[4]), bf2f(u.us[5]), bf2f(u.us[6]), bf2f(u.us[7]));
                *(float4*)d = lo; *(float4*)(d + 4) = hi;
            }
        }
        __syncthreads();
        for (int t = 0; t < 64; t++) {
            float4 wv = *(const float4*)&ws[t][mg * 4];
            float4 sv = *(const float4*)&ts[t * 128 + sg * 4];
            accT[0]  += wv.x * sv.x; accT[1]  += wv.x * sv.y; accT[2]  += wv.x * sv.z; accT[3]  += wv.x * sv.w;
            accT[4]  += wv.y * sv.x; accT[5]  += wv.y * sv.y; accT[6]  += wv.y * sv.z; accT[7]  += wv.y * sv.w;
            accT[8]  += wv.z * sv.x; accT[9]  += wv.z * sv.y; accT[10] += wv.z * sv.z; accT[11] += wv.z * sv.w;
            accT[12] += wv.w * sv.x; accT[13] += wv.w * sv.y; accT[14] += wv.w * sv.z; accT[15] += wv.w * sv.w;
            float wa = ws[t][mW];
            float4 wb = *(const float4*)&ws[t][m2];
            accW[0] += wa * wb.x; accW[1] += wa * wb.y;
            accW[2] += wa * wb.z; accW[3] += wa * wb.w;
        }
    }
    float* pb = part + (size_t)blockIdx.x * 5120;
#pragma unroll
    for (int i = 0; i < 16; i++) pb[i * 256 + tid] = accT[i];
#pragma unroll
    for (int i = 0; i < 4; i++) pb[4096 + i * 256 + tid] = accW[i];
}

// ---------------- reduce 1024 partials -> WtT [32,128], WtW [32,32] ----------------
__global__ __launch_bounds__(256) void memcell_reduce_kern(
    const float* __restrict__ part, float* __restrict__ WtT, float* __restrict__ WtW)
{
    int gid = blockIdx.x * 256 + threadIdx.x;   // 81920
    int j = gid % 5120, seg = gid / 5120;
    const float* p = part + (size_t)seg * 64 * 5120 + j;
    float s = 0.f;
#pragma unroll 8
    for (int k = 0; k < 64; k++) s += p[(size_t)k * 5120];
    int i = j >> 8, t = j & 255;
    if (j < 4096) {
        int sg = t & 31, mg = t >> 5;
        atomicAdd(&WtT[(mg * 4 + (i >> 2)) * 128 + sg * 4 + (i & 3)], s);
    } else {
        int i2 = i - 16;
        int mW = t & 31, m2 = (t >> 5) * 4;
        atomicAdd(&WtW[mW * 32 + m2 + i2], s);
    }
}

// ------- cell_v_new = cell_v + ALPHA*(WtT - WtW @ cell_v)  [32,128] -------
__global__ __launch_bounds__(256) void cvnew_kern(
    const float* __restrict__ cv, const float* __restrict__ WtW,
    const float* __restrict__ WtT, float* __restrict__ cvn)
{
    int idx = blockIdx.x * 256 + threadIdx.x;   // 4096
    int s = idx & 127, m = idx >> 7;
    float g = WtT[idx];
#pragma unroll
    for (int j = 0; j < 32; j++) g -= WtW[m * 32 + j] * cv[j * 128 + s];
    cvn[idx] = cv[idx] + ALPHA_F * g;
}

// ------- t_read = w @ cell_v_new, scattered to NCHW d0m [8,128,128,128] -------
__global__ __launch_bounds__(256) void memcell_read_kern(
    const float* __restrict__ wmat, const float* __restrict__ cvn, float* __restrict__ d0m)
{
    int t = blockIdx.x * 256 + threadIdx.x;
    int w2 = t & 127, h2 = (t >> 7) & 127, b = t >> 14;
    float wv[32];
    const float4* wp = (const float4*)(wmat + (size_t)t * 32);
#pragma unroll
    for (int i = 0; i < 8; i++) {
        float4 v = wp[i];
        wv[4 * i] = v.x; wv[4 * i + 1] = v.y; wv[4 * i + 2] = v.z; wv[4 * i + 3] = v.w;
    }
    float* ob = d0m + (size_t)b * 128 * 16384 + (h2 << 7) + w2;
    for (int s = 0; s < 128; s++) {
        float a = 0.f;
#pragma unroll
        for (int m = 0; m < 32; m++) a += wv[m] * cvn[m * 128 + s];
        ob[(size_t)s * 16384] = a;
    }
}

// ------- ConvTranspose2d(128->3, k4, s2, p1) + bias + silu, all 4 parities/thread -------
__global__ __launch_bounds__(256) void deconv_silu_kern(
    const float* __restrict__ in, const float* __restrict__ dw,
    const float* __restrict__ db, float* __restrict__ out)
{
    int g = blockIdx.x;                   // 512: b*64 + hb*8 + wb
    int wb = g & 7, hb = (g >> 3) & 7, b = g >> 6;
    int tx = threadIdx.x & 15, ty = threadIdx.x >> 4;
    int h2 = hb * 16 + ty, w2 = wb * 16 + tx;

    float mh[3], mw[3];
    int ihc[3], iwc[3];
#pragma unroll
    for (int a = 0; a < 3; a++) {
        int v = h2 - 1 + a;
        mh[a] = ((unsigned)v < 128u) ? 1.f : 0.f;
        ihc[a] = v < 0 ? 0 : (v > 127 ? 127 : v);
        v = w2 - 1 + a;
        mw[a] = ((unsigned)v < 128u) ? 1.f : 0.f;
        iwc[a] = v < 0 ? 0 : (v > 127 ? 127 : v);
    }
    const float* base = in + (size_t)b * 128 * 16384;
    const float* p[3][3];
    float msk[3][3];
#pragma unroll
    for (int a = 0; a < 3; a++)
#pragma unroll
        for (int c = 0; c < 3; c++) {
            p[a][c] = base + (ihc[a] << 7) + iwc[c];
            msk[a][c] = mh[a] * mw[c];
        }

    float acc[2][2][3];
#pragma unroll
    for (int ph = 0; ph < 2; ph++)
#pragma unroll
        for (int pw = 0; pw < 2; pw++)
#pragma unroll
            for (int co = 0; co < 3; co++) acc[ph][pw][co] = db[co];

    const int RA[4] = {0, 1, 1, 2}, RP[4] = {0, 0, 1, 1}, RK[4] = {3, 1, 2, 0};

    for (int ci = 0; ci < 128; ci++) {
        float t[3][3];
#pragma unroll
        for (int a = 0; a < 3; a++)
#pragma unroll
            for (int c = 0; c < 3; c++)
                t[a][c] = msk[a][c] * p[a][c][(size_t)ci << 14];
        const float* wc = dw + ci * 48;
#pragma unroll
        for (int ri = 0; ri < 4; ri++)
#pragma unroll
            for (int cj = 0; cj < 4; cj++) {
                float tv = t[RA[ri]][RA[cj]];
                int ph = RP[ri], pw = RP[cj];
                int widx = RK[ri] * 4 + RK[cj];
#pragma unroll
                for (int co = 0; co < 3; co++)
                    acc[ph][pw][co] += tv * wc[co * 16 + widx];
            }
    }
    int h = 2 * h2, w = 2 * w2;
#pragma unroll
    for (int ph = 0; ph < 2; ph++)
#pragma unroll
        for (int co = 0; co < 3; co++) {
            float2 v = make_float2(silu_f(acc[ph][0][co]), silu_f(acc[ph][1][co]));
            *(float2*)&out[(size_t)b * 3 * 65536 + (size_t)co * 65536 + ((size_t)(h + ph) << 8) + w] = v;
        }
}

extern "C" void kernel_launch(void* const* d_in, const int* in_sizes, int n_in,
                              void* d_out, int out_size, void* d_ws, size_t ws_size,
                              hipStream_t stream)
{
    const float* x      = (const float*)d_in[0];
    const float* e0n_w1 = (const float*)d_in[1];
    const float* e0n_b1 = (const float*)d_in[2];
    const float* e0n_w2 = (const float*)d_in[3];
    const float* e0n_b2 = (const float*)d_in[4];
    const float* e0s_w1 = (const float*)d_in[5];
    const float* e0s_b1 = (const float*)d_in[6];
    const float* e0s_w2 = (const float*)d_in[7];
    const float* e0s_b2 = (const float*)d_in[8];
    const float* d0_dw  = (const float*)d_in[9];
    const float* d0_db  = (const float*)d_in[10];
    const float* d0_cw  = (const float*)d_in[11];
    const float* d0_cb  = (const float*)d_in[12];
    const float* cell_k = (const float*)d_in[13];
    const float* cell_v = (const float*)d_in[14];
    float* outp = (float*)d_out;

    char* ws = (char*)d_ws;
    __hip_bfloat16* a_s    = (__hip_bfloat16*)(ws);
    __hip_bfloat16* t_star = (__hip_bfloat16*)(ws + 134217728);
    float* a_n    = (float*)(ws + 201326592);
    __hip_bfloat16* wt2 = (__hip_bfloat16*)(ws + 201326592);  // reuses a_n after conv2_n
    float* part   = (float*)(ws + 201850880);                 // 21 MB partials (a_n dead)
    float* z      = (float*)(ws + 234881024);
    float* wmat   = (float*)(ws + 243269632);
    float* WtW    = (float*)(ws + 260046848);
    float* WtT    = (float*)(ws + 260050944);
    float* cvn    = (float*)(ws + 260067328);
    float* d0m    = (float*)(ws);               // reuse a_s region
    float* dec1   = (float*)(ws + 67108864);    // reuse a_s region (tail)

    // n-branch encoder (a_n dead after conv2s2_silu)
    conv1_silu<16><<<2048, 256, 0, stream>>>(x, e0n_w1, e0n_b1, a_n);
    conv2s2_silu<16, 16><<<512, 256, 0, stream>>>(a_n, e0n_w2, e0n_b2, z);
    // s-branch encoder: NC8HW8 MFMA conv1 -> MFMA implicit-GEMM conv2 (bf16 t_star out)
    wprep_kern<<<576, 256, 0, stream>>>(e0s_w2, wt2);
    conv1s_mfma<<<4096, 256, 0, stream>>>(x, e0s_w1, e0s_b1, a_s);
    conv2s_mfma<<<2048, 256, 0, stream>>>(a_s, wt2, e0s_b2, t_star);
    // memcell
    memcell_w_kern<<<512, 256, 0, stream>>>(z, cell_k, wmat);
    hipMemsetAsync(WtW, 0, (1024 + 4096) * sizeof(float), stream);
    memcell_acc_kern<<<1024, 256, 0, stream>>>(wmat, t_star, part);
    memcell_reduce_kern<<<320, 256, 0, stream>>>(part, WtT, WtW);
    cvnew_kern<<<16, 256, 0, stream>>>(cell_v, WtW, WtT, cvn);
    memcell_read_kern<<<512, 256, 0, stream>>>(wmat, cvn, d0m);
    // decoder
    deconv_silu_kern<<<512, 256, 0, stream>>>(d0m, d0_dw, d0_db, dec1);
    conv1_silu<3><<<2048, 256, 0, stream>>>(dec1, d0_cw, d0_cb, outp);
}

// Round 12
// 363.117 us; speedup vs baseline: 1.2312x; 1.1119x over previous
//
#include <hip/hip_runtime.h>
#include <hip/hip_bf16.h>

// CPSFMemcellAutoencoder: B=8, 256x256 input, N=16, S=128, M=32, T=131072.
// Workspace layout (~260 MB):
//   [0, 134217728)            a_s   : NC8HW8 [8][16 cig][65536 hw][8 ci] bf16
//     REUSED: t64 at [0, 33554432)  : [T][64] f32 (decoder tap-GEMM out; a_s dead by then)
//   [134217728, 167772160)    t_star: [T,128] bf16 token-major
//   [201326592, 234881024)    a_n   : [8,16,256,256] f32 (n-branch)
//     REUSED: wt2  at +201326592 (294912 B, conv2_s weights bf16)
//     REUSED: part at +201850880 (1024 x 5120 f32 partials)
//     REUSED: Emat at +224000000 (32*64 f32; part dead after reduce)
//   [234881024, 243269632)    z     : [T,16] f32
//   [243269632, 260046848)    wmat  : [T,32] f32
//   [260046848, 260050944)    WtW   : [32,32] f32
//   [260050944, 260067328)    WtT   : [32,128] f32
//   [260067328, 260083712)    cvn   : [32,128] f32
//   dec1 at [67108864, 73400320)    : [8,3,256,256] f32

#define ALPHA_F 1e-6f

typedef __attribute__((ext_vector_type(8))) short bf16x8;
typedef __attribute__((ext_vector_type(4))) float f32x4;

__device__ __forceinline__ float silu_f(float x) {
    return x / (1.f + __expf(-x));
}

__device__ __forceinline__ short f2bf(float f) {
    __hip_bfloat16 h = __float2bfloat16(f);
    union { __hip_bfloat16 b; short s; } u; u.b = h; return u.s;
}

__device__ __forceinline__ float bf2f(unsigned short s) {
    union { unsigned u; float f; } c; c.u = (unsigned)s << 16; return c.f;
}

// ---------------- conv 3x3, Cin=3, stride 1, pad 1, + bias + silu (NCHW f32 out) ----------------
template<int CO>
__global__ __launch_bounds__(256) void conv1_silu(
    const float* __restrict__ x, const float* __restrict__ wgt,
    const float* __restrict__ bias, float* __restrict__ out)
{
    int idx = blockIdx.x * 256 + threadIdx.x;      // (b,h,w)
    int w = idx & 255, h = (idx >> 8) & 255, b = idx >> 16;
    const float* xb = x + (size_t)b * 3 * 65536;
    float in[27];
#pragma unroll
    for (int ci = 0; ci < 3; ci++)
#pragma unroll
        for (int ky = 0; ky < 3; ky++)
#pragma unroll
            for (int kx = 0; kx < 3; kx++) {
                int hh = h + ky - 1, ww = w + kx - 1;
                bool ok = ((unsigned)hh < 256u) && ((unsigned)ww < 256u);
                in[(ci * 3 + ky) * 3 + kx] = ok ? xb[(ci << 16) + (hh << 8) + ww] : 0.f;
            }
    float* ob = out + (size_t)b * CO * 65536 + (h << 8) + w;
#pragma unroll 4
    for (int co = 0; co < CO; co++) {
        float acc = bias[co];          // uniform index -> s_load
#pragma unroll
        for (int k = 0; k < 27; k++) acc += in[k] * wgt[co * 27 + k];
        ob[(size_t)co << 16] = silu_f(acc);
    }
}

// ---------------- s-branch conv1 as single-K-step MFMA GEMM ----------------
#define C1K 40   // padded k-stride (shorts)
__global__ __launch_bounds__(256) void conv1s_mfma(
    const float* __restrict__ x, const float* __restrict__ wgt,
    const float* __restrict__ bias, __hip_bfloat16* __restrict__ out)
{
    __shared__ __align__(16) short Ps[128 * C1K];  // [pixel][k]
    __shared__ __align__(16) short Ws[128 * C1K];  // [co][k]
    int tid = threadIdx.x;
    int g = blockIdx.x;                 // 4096: b*512 + rem
    int b = g >> 9, rem = g & 511;
    int h = rem >> 1, w0 = (rem & 1) * 128;

    union { short s[32]; float4 v4[4]; } row;
#pragma unroll
    for (int k = 0; k < 32; k++) row.s[k] = 0;
    if (tid < 128) {
        int wpix = w0 + tid;
        const float* xb = x + (size_t)b * 3 * 65536;
#pragma unroll
        for (int ci = 0; ci < 3; ci++)
#pragma unroll
            for (int ky = 0; ky < 3; ky++)
#pragma unroll
                for (int kx = 0; kx < 3; kx++) {
                    int hh = h + ky - 1, ww = wpix + kx - 1;
                    float v = 0.f;
                    if (((unsigned)hh < 256u) && ((unsigned)ww < 256u))
                        v = xb[(ci << 16) + (hh << 8) + ww];
                    row.s[ci * 9 + ky * 3 + kx] = f2bf(v);
                }
#pragma unroll
        for (int j = 0; j < 4; j++) *(float4*)&Ps[tid * C1K + j * 8] = row.v4[j];
    } else {
        int co = tid - 128;
#pragma unroll
        for (int k = 0; k < 27; k++) row.s[k] = f2bf(wgt[co * 27 + k]);
#pragma unroll
        for (int j = 0; j < 4; j++) *(float4*)&Ws[co * C1K + j * 8] = row.v4[j];
    }
    __syncthreads();

    int lane = tid & 63, wave = tid >> 6;
    int coH = (wave & 1) * 64, pxH = (wave >> 1) * 64;
    int r16 = lane & 15, koff = (lane >> 4) * 8;
    bf16x8 af[4], bfr[4];
#pragma unroll
    for (int mt = 0; mt < 4; mt++)
        af[mt] = *(bf16x8*)&Ws[(coH + mt * 16 + r16) * C1K + koff];
#pragma unroll
    for (int nt = 0; nt < 4; nt++)
        bfr[nt] = *(bf16x8*)&Ps[(pxH + nt * 16 + r16) * C1K + koff];
    f32x4 acc[4][4];
#pragma unroll
    for (int mt = 0; mt < 4; mt++)
#pragma unroll
        for (int nt = 0; nt < 4; nt++) {
#pragma unroll
            for (int r = 0; r < 4; r++) acc[mt][nt][r] = 0.f;
            acc[mt][nt] = __builtin_amdgcn_mfma_f32_16x16x32_bf16(
                af[mt], bfr[nt], acc[mt][nt], 0, 0, 0);
        }

    __hip_bfloat16* ob = out + (size_t)b * 16 * 65536 * 8;
#pragma unroll
    for (int mt = 0; mt < 4; mt++) {
        int cb = coH + mt * 16 + (lane >> 4) * 4;
        float4 bv = *(const float4*)&bias[cb];
        float bvals[4] = {bv.x, bv.y, bv.z, bv.w};
        int cig = cb >> 3, cof = cb & 7;
#pragma unroll
        for (int nt = 0; nt < 4; nt++) {
            int p = pxH + nt * 16 + r16;
            int hw = (h << 8) + w0 + p;
            union { short s[4]; float2 v; } u;
#pragma unroll
            for (int r = 0; r < 4; r++)
                u.s[r] = f2bf(silu_f(acc[mt][nt][r] + bvals[r]));
            *(float2*)&ob[((size_t)cig * 65536 + hw) * 8 + cof] = u.v;
        }
    }
}

// ---------------- weight prep: Wt[pos][co][ci] bf16 from W[co][ci][ky][kx] f32 ----------------
__global__ __launch_bounds__(256) void wprep_kern(
    const float* __restrict__ w, __hip_bfloat16* __restrict__ wt)
{
    int i = blockIdx.x * 256 + threadIdx.x;        // 147456
    int pos = i >> 14, rem = i & 16383;
    int co = rem >> 7, ci = rem & 127;
    wt[i] = __float2bfloat16(w[co * 1152 + ci * 9 + pos]);
}

// ------------- conv2_s implicit GEMM v11 (FROZEN at 80.5us, R11): 64tok x 128co, K=64 stages -------------
#define TK64 72
__global__ __launch_bounds__(256) void conv2s_mfma(
    const __hip_bfloat16* __restrict__ a_s,   // NC8HW8 [8][16][65536][8]
    const __hip_bfloat16* __restrict__ wt,    // [9][128co][128ci]
    const float* __restrict__ bias, __hip_bfloat16* __restrict__ out)  // [T][128] bf16
{
    __shared__ __align__(16) short As[64 * TK64];    //  9216 B
    __shared__ __align__(16) short Bs[128 * TK64];   // 18432 B
    int tid = threadIdx.x;
    int g = blockIdx.x;                 // 2048: b*256 + h2*2 + half
    int b = g >> 8, h2 = (g >> 1) & 127, w2base = (g & 1) * 64;
    int lane = tid & 63, wave = tid >> 6;
    int mrow = lane & 15, q = lane >> 4;

    f32x4 acc[2][4];   // [nt][mt]
#pragma unroll
    for (int i = 0; i < 2; i++)
#pragma unroll
        for (int j = 0; j < 4; j++)
#pragma unroll
            for (int r = 0; r < 4; r++) acc[i][j][r] = 0.f;

    const float4* ab8 = (const float4*)a_s + (size_t)b * 16 * 65536;
    int tokA = tid >> 2, cqA = tid & 3;         // A staging: token, ci8-group
    int w2A = w2base + tokA;

#pragma unroll 1
    for (int pos = 0; pos < 9; pos++) {
        int ky = pos / 3, kx = pos - 3 * ky;    // uniform
        int y = 2 * h2 - 1 + ky;
        int x = 2 * w2A - 1 + kx;
        bool okA = ((unsigned)y < 256u) && ((unsigned)x < 256u);
        int pix = ((y & 255) << 8) + (x & 255);
        const float4* wp4 = (const float4*)(wt + (size_t)pos * 16384);
#pragma unroll 1
        for (int cc = 0; cc < 2; cc++) {        // ci chunks of 64
            float4 a0 = make_float4(0.f, 0.f, 0.f, 0.f), a1 = a0;
            if (okA) {
                a0 = ab8[(size_t)(cc * 8 + cqA) << 16 | (unsigned)pix];
                a1 = ab8[(size_t)(cc * 8 + cqA + 4) << 16 | (unsigned)pix];
            }
            int s0 = tid, s1 = tid + 256;
            float4 b0 = wp4[(s0 >> 3) * 16 + cc * 8 + (s0 & 7)];
            float4 b1 = wp4[(s1 >> 3) * 16 + cc * 8 + (s1 & 7)];
            __syncthreads();                    // previous stage's LDS reads done
            *(float4*)&As[tokA * TK64 + cqA * 8]       = a0;
            *(float4*)&As[tokA * TK64 + (cqA + 4) * 8] = a1;
            *(float4*)&Bs[(s0 >> 3) * TK64 + (s0 & 7) * 8] = b0;
            *(float4*)&Bs[(s1 >> 3) * TK64 + (s1 & 7) * 8] = b1;
            int s2 = tid + 512, s3 = tid + 768;
            float4 b2 = wp4[(s2 >> 3) * 16 + cc * 8 + (s2 & 7)];
            float4 b3 = wp4[(s3 >> 3) * 16 + cc * 8 + (s3 & 7)];
            *(float4*)&Bs[(s2 >> 3) * TK64 + (s2 & 7) * 8] = b2;
            *(float4*)&Bs[(s3 >> 3) * TK64 + (s3 & 7) * 8] = b3;
            __syncthreads();
#pragma unroll
            for (int c2 = 0; c2 < 2; c2++) {
                int ko = c2 * 32 + q * 8;
                bf16x8 afr[4], bfr[2];
#pragma unroll
                for (int mt = 0; mt < 4; mt++)
                    afr[mt] = *(bf16x8*)&As[(mt * 16 + mrow) * TK64 + ko];
#pragma unroll
                for (int nt = 0; nt < 2; nt++)
                    bfr[nt] = *(bf16x8*)&Bs[(wave * 32 + nt * 16 + mrow) * TK64 + ko];
#pragma unroll
                for (int nt = 0; nt < 2; nt++)
#pragma unroll
                    for (int mt = 0; mt < 4; mt++)
                        acc[nt][mt] = __builtin_amdgcn_mfma_f32_16x16x32_bf16(
                            afr[mt], bfr[nt], acc[nt][mt], 0, 0, 0);
            }
        }
    }
    int rowg = q * 4;
    size_t tbase = (size_t)g * 64;
#pragma unroll
    for (int nt = 0; nt < 2; nt++) {
        int co = wave * 32 + nt * 16 + mrow;
        float bvs = bias[co];
#pragma unroll
        for (int mt = 0; mt < 4; mt++)
#pragma unroll
            for (int r = 0; r < 4; r++) {
                int m = mt * 16 + rowg + r;
                out[(tbase + m) * 128 + co] =
                    __float2bfloat16(silu_f(acc[nt][mt][r] + bvs));
            }
    }
}

// ------------- conv 3x3, stride 2, pad 1, + bias + silu, token-major out (n-branch) -------------
template<int CI, int CO>
__global__ __launch_bounds__(256) void conv2s2_silu(
    const float* __restrict__ in, const float* __restrict__ wgt,
    const float* __restrict__ bias, float* __restrict__ out)
{
    int idx = blockIdx.x * 256 + threadIdx.x;      // token (b,h2,w2)
    int w2 = idx & 127, h2 = (idx >> 7) & 127, b = idx >> 14;
    const float* ib = in + (size_t)b * CI * 65536;
    float acc[CO];
#pragma unroll
    for (int co = 0; co < CO; co++) acc[co] = bias[co];
    int h0 = 2 * h2 - 1, w0 = 2 * w2 - 1;
    for (int ci = 0; ci < CI; ci++) {
        float t[9];
#pragma unroll
        for (int ky = 0; ky < 3; ky++)
#pragma unroll
            for (int kx = 0; kx < 3; kx++) {
                int hh = h0 + ky, ww = w0 + kx;
                bool ok = ((unsigned)hh < 256u) && ((unsigned)ww < 256u);
                t[ky * 3 + kx] = ok ? ib[((size_t)ci << 16) + (hh << 8) + ww] : 0.f;
            }
#pragma unroll
        for (int co = 0; co < CO; co++)
#pragma unroll
            for (int k = 0; k < 9; k++)
                acc[co] += t[k] * wgt[(co * CI + ci) * 9 + k];
    }
    float* ob = out + (size_t)idx * CO;
#pragma unroll
    for (int co = 0; co < CO; co++) ob[co] = silu_f(acc[co]);
}

// ---------------- softmax(z @ cell_k^T / 4) -> w [T,32] ----------------
__global__ __launch_bounds__(256) void memcell_w_kern(
    const float* __restrict__ z, const float* __restrict__ ck, float* __restrict__ wout)
{
    int t = blockIdx.x * 256 + threadIdx.x;
    float zv[16];
    const float4* zp = (const float4*)(z + (size_t)t * 16);
#pragma unroll
    for (int i = 0; i < 4; i++) {
        float4 v = zp[i];
        zv[4 * i] = v.x; zv[4 * i + 1] = v.y; zv[4 * i + 2] = v.z; zv[4 * i + 3] = v.w;
    }
    float lg[32]; float mx = -1e30f;
#pragma unroll
    for (int m = 0; m < 32; m++) {
        float a = 0.f;
#pragma unroll
        for (int n = 0; n < 16; n++) a += zv[n] * ck[m * 16 + n];
        a *= 0.25f;
        lg[m] = a; mx = fmaxf(mx, a);
    }
    float s = 0.f;
#pragma unroll
    for (int m = 0; m < 32; m++) { lg[m] = __expf(lg[m] - mx); s += lg[m]; }
    float inv = 1.f / s;
    float4* wp = (float4*)(wout + (size_t)t * 32);
#pragma unroll
    for (int m = 0; m < 8; m++)
        wp[m] = make_float4(lg[4 * m] * inv, lg[4 * m + 1] * inv,
                            lg[4 * m + 2] * inv, lg[4 * m + 3] * inv);
}

// ---------------- WtW/WtT partials: 1024 blocks x 128 tokens, no atomics ----------------
__global__ __launch_bounds__(256) void memcell_acc_kern(
    const float* __restrict__ wmat, const __hip_bfloat16* __restrict__ tstar,
    float* __restrict__ part)
{
    __shared__ float ws[64][32];     // 8 KB
    __shared__ float ts[64 * 128];   // 32 KB
    int tid = threadIdx.x;
    int sg = tid & 31, mg = tid >> 5;
    int mW = tid & 31, m2 = (tid >> 5) * 4;
    float accT[16], accW[4];
#pragma unroll
    for (int i = 0; i < 16; i++) accT[i] = 0.f;
#pragma unroll
    for (int i = 0; i < 4; i++) accW[i] = 0.f;

#pragma unroll 1
    for (int cc = 0; cc < 2; cc++) {
        int c = blockIdx.x * 2 + cc;
        size_t base = (size_t)c * 64;
        __syncthreads();
        {
            const float4* src = (const float4*)(wmat + base * 32);
            float4* dst = (float4*)&ws[0][0];
#pragma unroll
            for (int i = 0; i < 2; i++) dst[tid + 256 * i] = src[tid + 256 * i];
            const float4* src2 = (const float4*)(tstar + base * 128);
#pragma unroll
            for (int i = 0; i < 4; i++) {
                union { float4 v; unsigned short us[8]; } u;
                u.v = src2[tid + 256 * i];
                float* d = &ts[(tid + 256 * i) * 8];
                float4 lo = make_float4(bf2f(u.us[0]), bf2f(u.us[1]), bf2f(u.us[2]), bf2f(u.us[3]));
                float4 hi = make_float4(bf2f(u.us[4]), bf2f(u.us[5]), bf2f(u.us[6]), bf2f(u.us[7]));
                *(float4*)d = lo; *(float4*)(d + 4) = hi;
            }
        }
        __syncthreads();
        for (int t = 0; t < 64; t++) {
            float4 wv = *(const float4*)&ws[t][mg * 4];
            float4 sv = *(const float4*)&ts[t * 128 + sg * 4];
            accT[0]  += wv.x * sv.x; accT[1]  += wv.x * sv.y; accT[2]  += wv.x * sv.z; accT[3]  += wv.x * sv.w;
            accT[4]  += wv.y * sv.x; accT[5]  += wv.y * sv.y; accT[6]  += wv.y * sv.z; accT[7]  += wv.y * sv.w;
            accT[8]  += wv.z * sv.x; accT[9]  += wv.z * sv.y; accT[10] += wv.z * sv.z; accT[11] += wv.z * sv.w;
            accT[12] += wv.w * sv.x; accT[13] += wv.w * sv.y; accT[14] += wv.w * sv.z; accT[15] += wv.w * sv.w;
            float wa = ws[t][mW];
            float4 wb = *(const float4*)&ws[t][m2];
            accW[0] += wa * wb.x; accW[1] += wa * wb.y;
            accW[2] += wa * wb.z; accW[3] += wa * wb.w;
        }
    }
    float* pb = part + (size_t)blockIdx.x * 5120;
#pragma unroll
    for (int i = 0; i < 16; i++) pb[i * 256 + tid] = accT[i];
#pragma unroll
    for (int i = 0; i < 4; i++) pb[4096 + i * 256 + tid] = accW[i];
}

// ---------------- reduce 1024 partials -> WtT [32,128], WtW [32,32] ----------------
__global__ __launch_bounds__(256) void memcell_reduce_kern(
    const float* __restrict__ part, float* __restrict__ WtT, float* __restrict__ WtW)
{
    int gid = blockIdx.x * 256 + threadIdx.x;   // 81920
    int j = gid % 5120, seg = gid / 5120;
    const float* p = part + (size_t)seg * 64 * 5120 + j;
    float s = 0.f;
#pragma unroll 8
    for (int k = 0; k < 64; k++) s += p[(size_t)k * 5120];
    int i = j >> 8, t = j & 255;
    if (j < 4096) {
        int sg = t & 31, mg = t >> 5;
        atomicAdd(&WtT[(mg * 4 + (i >> 2)) * 128 + sg * 4 + (i & 3)], s);
    } else {
        int i2 = i - 16;
        int mW = t & 31, m2 = (t >> 5) * 4;
        atomicAdd(&WtW[mW * 32 + m2 + i2], s);
    }
}

// ------- cell_v_new = cell_v + ALPHA*(WtT - WtW @ cell_v)  [32,128] -------
__global__ __launch_bounds__(256) void cvnew_kern(
    const float* __restrict__ cv, const float* __restrict__ WtW,
    const float* __restrict__ WtT, float* __restrict__ cvn)
{
    int idx = blockIdx.x * 256 + threadIdx.x;   // 4096
    int s = idx & 127, m = idx >> 7;
    float g = WtT[idx];
#pragma unroll
    for (int j = 0; j < 32; j++) g -= WtW[m * 32 + j] * cv[j * 128 + s];
    cvn[idx] = cv[idx] + ALPHA_F * g;
}

// ------- E[m][pos*4+co] = sum_ci cvn[m][ci] * dw[ci][co][kh][kw]  (decoder folded weights) -------
// E is [32][64]: pos = kh*4+kw in [0,16), co in [0,4) (co=3 is zero pad for float4 gather loads)
__global__ __launch_bounds__(256) void emat_kern(
    const float* __restrict__ cvn, const float* __restrict__ dw, float* __restrict__ E)
{
    int idx = blockIdx.x * 256 + threadIdx.x;   // 2048
    int m = idx >> 6, j = idx & 63;
    int pos = j >> 2, co = j & 3;
    float s = 0.f;
    if (co < 3) {
        const float* cv = cvn + m * 128;        // uniform per 64-lane group -> s_loads
        for (int ci = 0; ci < 128; ci++)
            s += cv[ci] * dw[ci * 48 + co * 16 + pos];
    }
    E[idx] = s;
}

// ------- t64[T][64] = wmat[T,32] @ E[32,64]  (decoder tap values, f32) -------
__global__ __launch_bounds__(256) void tread64_kern(
    const float* __restrict__ wmat, const float* __restrict__ E, float* __restrict__ t64)
{
    int t = blockIdx.x * 256 + threadIdx.x;
    float wv[32];
    const float4* wp = (const float4*)(wmat + (size_t)t * 32);
#pragma unroll
    for (int i = 0; i < 8; i++) {
        float4 v = wp[i];
        wv[4 * i] = v.x; wv[4 * i + 1] = v.y; wv[4 * i + 2] = v.z; wv[4 * i + 3] = v.w;
    }
    f32x4 acc[16];
#pragma unroll
    for (int i = 0; i < 16; i++)
#pragma unroll
        for (int r = 0; r < 4; r++) acc[i][r] = 0.f;
    const f32x4* E4 = (const f32x4*)E;
#pragma unroll 4
    for (int m = 0; m < 32; m++) {
        float wm = wv[m];
#pragma unroll
        for (int i = 0; i < 16; i++) {
            f32x4 e = E4[m * 16 + i];           // uniform -> s_load_dwordx4
#pragma unroll
            for (int r = 0; r < 4; r++) acc[i][r] += wm * e[r];
        }
    }
    f32x4* ob = (f32x4*)(t64 + (size_t)t * 64);
#pragma unroll
    for (int i = 0; i < 16; i++) ob[i] = acc[i];
}

// ------- decoder gather: dec1 = silu(sum of 4 taps from t64 + bias), all 4 parities/thread -------
// Same RA/RP/RK tap->output maps as the verified deconv (R4-R11); ci-sum is pre-folded into t64.
__global__ __launch_bounds__(256) void dec_gather_kern(
    const float* __restrict__ t64, const float* __restrict__ db, float* __restrict__ out)
{
    int g = blockIdx.x;                   // 512: b*64 + hb*8 + wb
    int wb = g & 7, hb = (g >> 3) & 7, b = g >> 6;
    int tx = threadIdx.x & 15, ty = threadIdx.x >> 4;
    int h2 = hb * 16 + ty, w2 = wb * 16 + tx;

    float mh[3], mw[3];
    int ihc[3], iwc[3];
#pragma unroll
    for (int a = 0; a < 3; a++) {
        int v = h2 - 1 + a;
        mh[a] = ((unsigned)v < 128u) ? 1.f : 0.f;
        ihc[a] = v < 0 ? 0 : (v > 127 ? 127 : v);
        v = w2 - 1 + a;
        mw[a] = ((unsigned)v < 128u) ? 1.f : 0.f;
        iwc[a] = v < 0 ? 0 : (v > 127 ? 127 : v);
    }
    float acc[2][2][3];
#pragma unroll
    for (int ph = 0; ph < 2; ph++)
#pragma unroll
        for (int pw = 0; pw < 2; pw++)
#pragma unroll
            for (int co = 0; co < 3; co++) acc[ph][pw][co] = db[co];

    const int RA[4] = {0, 1, 1, 2}, RP[4] = {0, 0, 1, 1}, RK[4] = {3, 1, 2, 0};
    const float* tb = t64 + (size_t)b * 16384 * 64;
#pragma unroll
    for (int ri = 0; ri < 4; ri++)
#pragma unroll
        for (int cj = 0; cj < 4; cj++) {
            int a = RA[ri], c = RA[cj];
            float m = mh[a] * mw[c];
            int tok = (ihc[a] << 7) + iwc[c];
            int pos = RK[ri] * 4 + RK[cj];
            float4 v = *(const float4*)&tb[(size_t)tok * 64 + pos * 4];
            int ph = RP[ri], pw = RP[cj];
            acc[ph][pw][0] += m * v.x;
            acc[ph][pw][1] += m * v.y;
            acc[ph][pw][2] += m * v.z;
        }
    int h = 2 * h2, w = 2 * w2;
#pragma unroll
    for (int ph = 0; ph < 2; ph++)
#pragma unroll
        for (int co = 0; co < 3; co++) {
            float2 v = make_float2(silu_f(acc[ph][0][co]), silu_f(acc[ph][1][co]));
            *(float2*)&out[(size_t)b * 3 * 65536 + (size_t)co * 65536 + ((size_t)(h + ph) << 8) + w] = v;
        }
}

extern "C" void kernel_launch(void* const* d_in, const int* in_sizes, int n_in,
                              void* d_out, int out_size, void* d_ws, size_t ws_size,
                              hipStream_t stream)
{
    const float* x      = (const float*)d_in[0];
    const float* e0n_w1 = (const float*)d_in[1];
    const float* e0n_b1 = (const float*)d_in[2];
    const float* e0n_w2 = (const float*)d_in[3];
    const float* e0n_b2 = (const float*)d_in[4];
    const float* e0s_w1 = (const float*)d_in[5];
    const float* e0s_b1 = (const float*)d_in[6];
    const float* e0s_w2 = (const float*)d_in[7];
    const float* e0s_b2 = (const float*)d_in[8];
    const float* d0_dw  = (const float*)d_in[9];
    const float* d0_db  = (const float*)d_in[10];
    const float* d0_cw  = (const float*)d_in[11];
    const float* d0_cb  = (const float*)d_in[12];
    const float* cell_k = (const float*)d_in[13];
    const float* cell_v = (const float*)d_in[14];
    float* outp = (float*)d_out;

    char* ws = (char*)d_ws;
    __hip_bfloat16* a_s    = (__hip_bfloat16*)(ws);
    __hip_bfloat16* t_star = (__hip_bfloat16*)(ws + 134217728);
    float* a_n    = (float*)(ws + 201326592);
    __hip_bfloat16* wt2 = (__hip_bfloat16*)(ws + 201326592);  // reuses a_n after conv2_n
    float* part   = (float*)(ws + 201850880);                 // 21 MB partials (a_n dead)
    float* Emat   = (float*)(ws + 224000000);                 // 8 KB (part dead after reduce)
    float* z      = (float*)(ws + 234881024);
    float* wmat   = (float*)(ws + 243269632);
    float* WtW    = (float*)(ws + 260046848);
    float* WtT    = (float*)(ws + 260050944);
    float* cvn    = (float*)(ws + 260067328);
    float* t64    = (float*)(ws);               // reuse a_s region (dead after conv2s)
    float* dec1   = (float*)(ws + 67108864);    // reuse a_s region (tail)

    // n-branch encoder (a_n dead after conv2s2_silu)
    conv1_silu<16><<<2048, 256, 0, stream>>>(x, e0n_w1, e0n_b1, a_n);
    conv2s2_silu<16, 16><<<512, 256, 0, stream>>>(a_n, e0n_w2, e0n_b2, z);
    // s-branch encoder: NC8HW8 MFMA conv1 -> MFMA implicit-GEMM conv2 (bf16 t_star out)
    wprep_kern<<<576, 256, 0, stream>>>(e0s_w2, wt2);
    conv1s_mfma<<<4096, 256, 0, stream>>>(x, e0s_w1, e0s_b1, a_s);
    conv2s_mfma<<<2048, 256, 0, stream>>>(a_s, wt2, e0s_b2, t_star);
    // memcell
    memcell_w_kern<<<512, 256, 0, stream>>>(z, cell_k, wmat);
    hipMemsetAsync(WtW, 0, (1024 + 4096) * sizeof(float), stream);
    memcell_acc_kern<<<1024, 256, 0, stream>>>(wmat, t_star, part);
    memcell_reduce_kern<<<320, 256, 0, stream>>>(part, WtT, WtW);
    cvnew_kern<<<16, 256, 0, stream>>>(cell_v, WtW, WtT, cvn);
    // decoder: fold deconv weights through cvn, then gather from wmat-space
    emat_kern<<<8, 256, 0, stream>>>(cvn, d0_dw, Emat);
    tread64_kern<<<512, 256, 0, stream>>>(wmat, Emat, t64);
    dec_gather_kern<<<512, 256, 0, stream>>>(t64, d0_db, dec1);
    conv1_silu<3><<<2048, 256, 0, stream>>>(dec1, d0_cw, d0_cb, outp);
}